// Round 3
// baseline (662.295 us; speedup 1.0000x reference)
//
#include <hip/hip_runtime.h>

#define B_    32
#define NV    1556
#define NI    256
#define NT    1812          // NV + NI
#define D_    512
#define IMGD  2048
#define MV    (B_*NV)       // 49792 = 389*128
#define MI    (B_*NI)       // 8192  = 64*128
#define MQ    (B_*NT)       // 57984
#define SCALE_ 0.08838834764831845f   // (512/4)^-0.5

typedef _Float16 half_t;
typedef __attribute__((ext_vector_type(4))) _Float16 half4;
typedef __attribute__((ext_vector_type(8))) _Float16 half8;
typedef __attribute__((ext_vector_type(4))) float floatx4;

__device__ __forceinline__ void gload16(const void* g, void* l) {
    __builtin_amdgcn_global_load_lds(
        (const __attribute__((address_space(1))) void*)g,
        (__attribute__((address_space(3))) void*)l, 16, 0, 0);
}

// Swizzle: LDS keeps 64B per row (4x 16B slots). Slot s of row r holds global
// k-chunk s ^ ((r>>1)&3). Stage source permutes chunks within the row (quad
// still fetches 64B contiguous -> coalescing preserved); fragment read applies
// the same involution -> 2-way bank aliasing only (free).
// Pipeline: 3 LDS buffers, prefetch depth 2, counted s_waitcnt vmcnt(N) so
// stage(t+1) stays in flight ACROSS the barrier (T4); raw s_barrier, no drain.

// ---------------------------------------------------------------- convert
__global__ __launch_bounds__(256) void convert_all(
    const float* __restrict__ verts, const float* __restrict__ img,
    const float* __restrict__ w2, const float* __restrict__ w3,
    const float* __restrict__ w4, const float* __restrict__ w5,
    half_t* __restrict__ o0, half_t* __restrict__ o1, half_t* __restrict__ o2,
    half_t* __restrict__ o3, half_t* __restrict__ o4, half_t* __restrict__ o5)
{
    const long E0 = (long)MV * D_;
    const long E1 = (long)MI * IMGD;
    const long E2 = (long)D_ * IMGD;
    const long E3 = (long)D_ * D_;
    const long total4 = (E0 + E1 + E2 + 3 * E3) / 4;
    for (long i = blockIdx.x * (long)blockDim.x + threadIdx.x; i < total4;
         i += (long)gridDim.x * blockDim.x) {
        long e = i * 4;
        const float* s; half_t* d;
        if (e < E0)              { s = verts; d = o0; }
        else if ((e -= E0) < E1) { s = img;   d = o1; }
        else if ((e -= E1) < E2) { s = w2;    d = o2; }
        else if ((e -= E2) < E3) { s = w3;    d = o3; }
        else if ((e -= E3) < E3) { s = w4;    d = o4; }
        else                     { e -= E3; s = w5; d = o5; }
        float4 x = *(const float4*)(s + e);
        half4 h = { (half_t)x.x, (half_t)x.y, (half_t)x.z, (half_t)x.w };
        *(half4*)(d + e) = h;
    }
}

// pwt[d,e] = proj_w[e,d]  (f16)
__global__ __launch_bounds__(256) void transpose_pw(
    const float* __restrict__ P, half_t* __restrict__ pwt)
{
    const int n = blockIdx.x;
    for (int d = threadIdx.x; d < 512; d += 256)
        pwt[(size_t)n * 512 + d] = (half_t)P[(size_t)d * 512 + n];
}

// bias2[f] = sum_d pb[d]*F[f,d] + fb[f]
__global__ __launch_bounds__(256) void make_bias2(
    const float* __restrict__ pb, const float* __restrict__ F,
    const float* __restrict__ fb, float* __restrict__ bias2)
{
    const int n = blockIdx.x * 256 + threadIdx.x;
    float s = fb[n];
    for (int d = 0; d < 512; d++) s += pb[d] * F[(size_t)n * 512 + d];
    bias2[n] = s;
}

// ---------------------------------------------------------------- basic 128x128 GEMM
template<int MODE>
__global__ __launch_bounds__(256) void gemm_bt(
    const half_t* __restrict__ A, const half_t* __restrict__ Bw,
    const float* __restrict__ bias, int K, half_t* __restrict__ Ch)
{
    __shared__ __align__(16) half_t As[3][128 * 32];
    __shared__ __align__(16) half_t Bs[3][128 * 32];
    const int tid  = threadIdx.x;
    const int lane = tid & 63;
    const int wave = tid >> 6;
    const int quad = lane >> 4, l15 = lane & 15;
    const int wr = (wave >> 1) * 64;
    const int wc = (wave & 1) * 64;
    const int bm = blockIdx.x, bn = blockIdx.y;

    floatx4 acc[4][4];
#pragma unroll
    for (int i = 0; i < 4; i++)
#pragma unroll
        for (int j = 0; j < 4; j++) acc[i][j] = (floatx4){0.f, 0.f, 0.f, 0.f};

    const int r0  = tid >> 2;
    const int akp = ((tid & 3) ^ ((tid >> 3) & 3)) * 8;   // swizzled k-chunk
    const half_t* ag0 = A  + (size_t)(bm * 128 + r0) * K + akp;
    const half_t* ag1 = A  + (size_t)(bm * 128 + 64 + r0) * K + akp;
    const half_t* bg0 = Bw + (size_t)(bn * 128 + r0) * K + akp;
    const half_t* bg1 = Bw + (size_t)(bn * 128 + 64 + r0) * K + akp;

    auto stage = [&](int t, int buf) {
        const int k0 = t * 32;
        gload16(ag0 + k0, &As[buf][tid * 8]);
        gload16(ag1 + k0, &As[buf][(tid + 256) * 8]);
        gload16(bg0 + k0, &Bs[buf][tid * 8]);
        gload16(bg1 + k0, &Bs[buf][(tid + 256) * 8]);
    };
    const int frr = l15 * 32 + ((quad ^ ((l15 >> 1) & 3)) << 3);
    auto do_tile = [&](int buf) {
        half8 a[4], b[4];
#pragma unroll
        for (int i = 0; i < 4; i++)
            a[i] = *(const half8*)&As[buf][(wr + i * 16) * 32 + frr];
#pragma unroll
        for (int j = 0; j < 4; j++)
            b[j] = *(const half8*)&Bs[buf][(wc + j * 16) * 32 + frr];
#pragma unroll
        for (int i = 0; i < 4; i++)
#pragma unroll
            for (int j = 0; j < 4; j++)
                acc[i][j] = __builtin_amdgcn_mfma_f32_16x16x32_f16(
                    a[i], b[j], acc[i][j], 0, 0, 0);
    };

    const int NIT = K >> 5;
    stage(0, 0);
    stage(1, 1);
    int cur = 0;
    for (int t = 0; t < NIT - 1; ++t) {
        asm volatile("s_waitcnt vmcnt(4) lgkmcnt(0)" ::: "memory");
        __builtin_amdgcn_s_barrier();
        asm volatile("" ::: "memory");
        int nb = cur + 2; if (nb >= 3) nb -= 3;
        if (t + 2 < NIT) stage(t + 2, nb);
        do_tile(cur);
        cur++; if (cur == 3) cur = 0;
    }
    asm volatile("s_waitcnt vmcnt(0) lgkmcnt(0)" ::: "memory");
    __builtin_amdgcn_s_barrier();
    asm volatile("" ::: "memory");
    do_tile(cur);

    const int colbase = bn * 128 + wc + l15;
    const int rowbase = bm * 128 + wr + (quad << 2);
#pragma unroll
    for (int i = 0; i < 4; i++)
#pragma unroll
        for (int j = 0; j < 4; j++) {
            const int col = colbase + j * 16;
            const float bv = (MODE == 0) ? bias[col] : 0.f;
#pragma unroll
            for (int r = 0; r < 4; r++) {
                const int grow = rowbase + i * 16 + r;
                Ch[(size_t)grow * D_ + col] = (half_t)(acc[i][j][r] + bv);
            }
        }
}

// ---------------------------------------------------------------- full-N GEMM (128 rows x 512 cols)
template<int MODE, int TA, int COFF>
__global__ __launch_bounds__(512, 2) void gemm_fn(
    const half_t* __restrict__ A, const half_t* __restrict__ A2,
    const half_t* __restrict__ Bw, const half_t* __restrict__ Bw2,
    const float* __restrict__ bias, const float* __restrict__ aux,
    const half_t* __restrict__ vres, half_t* __restrict__ outp,
    float* __restrict__ fout)
{
    __shared__ __align__(16) half_t As[3][128 * 32];   // 24 KB
    __shared__ __align__(16) half_t Bs[3][512 * 32];   // 96 KB
    // red[512] + scale_l[128] aliased onto As[0] (dead after K-loop)
    float* red     = (float*)&As[0][0];
    float* scale_l = red + 512;

    const int tid = threadIdx.x, lane = tid & 63, wave = tid >> 6;
    const int rg = wave >> 2, cg = wave & 3;
    const int quad = lane >> 4, l15 = lane & 15;
    const int bm = blockIdx.x;

    const int arow = tid >> 2;
    const int akp  = ((tid & 3) ^ ((tid >> 3) & 3)) * 8;   // swizzled k-chunk
    const int gr_a = bm * 128 + arow;
    const half_t* ag0 = A + (size_t)gr_a * 512 + akp;
    const half_t* ag1 = nullptr;
    if (MODE == 3) {
        const int b = gr_a / NV, t = gr_a - b * NV;
        ag1 = A2 + ((size_t)b * NT + t) * 512 + akp;
    }
    size_t boff[4];
#pragma unroll
    for (int s = 0; s < 4; s++)
        boff[s] = (size_t)(arow + 128 * s) * 512 + akp;

    floatx4 acc[4][8];
#pragma unroll
    for (int i = 0; i < 4; i++)
#pragma unroll
        for (int j = 0; j < 8; j++) acc[i][j] = (floatx4){0.f, 0.f, 0.f, 0.f};

    const int NIT = (MODE == 3) ? 32 : 16;
    auto stage = [&](int t, int buf) {
        const half_t* ag = ag0;
        const half_t* bb = Bw;
        if (MODE == 3 && t >= 16) { ag = ag1; bb = Bw2; }
        const int k0 = (t & 15) * 32;
        gload16(ag + k0, &As[buf][tid * 8]);
#pragma unroll
        for (int s = 0; s < 4; s++)
            gload16(bb + boff[s] + k0, &Bs[buf][(tid + 512 * s) * 8]);
    };
    const int frr = l15 * 32 + ((quad ^ ((l15 >> 1) & 3)) << 3);
    auto do_tile = [&](int buf) {
        half8 a[4], b[8];
#pragma unroll
        for (int i = 0; i < 4; i++)
            a[i] = *(const half8*)&As[buf][(rg * 64 + i * 16) * 32 + frr];
#pragma unroll
        for (int j = 0; j < 8; j++)
            b[j] = *(const half8*)&Bs[buf][(cg * 128 + j * 16) * 32 + frr];
#pragma unroll
        for (int i = 0; i < 4; i++)
#pragma unroll
            for (int j = 0; j < 8; j++)
                acc[i][j] = __builtin_amdgcn_mfma_f32_16x16x32_f16(
                    a[i], b[j], acc[i][j], 0, 0, 0);
    };

    stage(0, 0);
    stage(1, 1);
    int cur = 0;
    for (int t = 0; t < NIT - 1; ++t) {
        asm volatile("s_waitcnt vmcnt(5) lgkmcnt(0)" ::: "memory");
        __builtin_amdgcn_s_barrier();
        asm volatile("" ::: "memory");
        int nb = cur + 2; if (nb >= 3) nb -= 3;
        if (t + 2 < NIT) stage(t + 2, nb);
        do_tile(cur);
        cur++; if (cur == 3) cur = 0;
    }
    asm volatile("s_waitcnt vmcnt(0) lgkmcnt(0)" ::: "memory");
    __builtin_amdgcn_s_barrier();
    asm volatile("" ::: "memory");
    do_tile(cur);

    if (MODE == 3) {
#pragma unroll
        for (int j = 0; j < 8; j++) {
            const int col = cg * 128 + j * 16 + l15;
            const float bv = bias[col];
#pragma unroll
            for (int i = 0; i < 4; i++)
#pragma unroll
                for (int r = 0; r < 4; r++) {
                    const int gr = bm * 128 + rg * 64 + i * 16 + quad * 4 + r;
                    const size_t idx = (size_t)gr * 512 + col;
                    fout[idx] = acc[i][j][r] + bv + (float)vres[idx];
                }
        }
        return;
    }

    __syncthreads();   // all waves done reading As[0] before red-alias writes

    // ---- bias + row sum-of-squares
    float ssq[4][4];
#pragma unroll
    for (int i = 0; i < 4; i++)
#pragma unroll
        for (int r = 0; r < 4; r++) ssq[i][r] = 0.f;
#pragma unroll
    for (int j = 0; j < 8; j++) {
        const float bv = bias[cg * 128 + j * 16 + l15];
#pragma unroll
        for (int i = 0; i < 4; i++)
#pragma unroll
            for (int r = 0; r < 4; r++) {
                float v = acc[i][j][r] + bv;
                acc[i][j][r] = v;
                ssq[i][r] += v * v;
            }
    }
#pragma unroll
    for (int i = 0; i < 4; i++)
#pragma unroll
        for (int r = 0; r < 4; r++)
#pragma unroll
            for (int m = 1; m < 16; m <<= 1)
                ssq[i][r] += __shfl_xor(ssq[i][r], m, 64);
    if (l15 == 0) {
#pragma unroll
        for (int i = 0; i < 4; i++)
#pragma unroll
            for (int r = 0; r < 4; r++)
                red[cg * 128 + rg * 64 + i * 16 + quad * 4 + r] = ssq[i][r];
    }
    __syncthreads();
    if (tid < 128)
        scale_l[tid] = 1.f / fmaxf(
            sqrtf(red[tid] + red[128 + tid] + red[256 + tid] + red[384 + tid]),
            1e-12f);
    __syncthreads();

    float sc[4][4];
    int rowb[4][4], rowt[4][4];
#pragma unroll
    for (int i = 0; i < 4; i++)
#pragma unroll
        for (int r = 0; r < 4; r++) {
            const int li = rg * 64 + i * 16 + quad * 4 + r;
            sc[i][r] = scale_l[li];
            const int gr = bm * 128 + li;
            const int b = gr / TA;
            rowb[i][r] = b;
            rowt[i][r] = gr - b * TA;
        }
    __syncthreads();   // scale_l/red fully read before any LDS reuse

    if (MODE == 1) {
        size_t ro[4][4];
        float dot[4][4];
#pragma unroll
        for (int i = 0; i < 4; i++)
#pragma unroll
            for (int r = 0; r < 4; r++) {
                ro[i][r] = ((size_t)rowb[i][r] * NT + COFF + rowt[i][r]) * 512;
                dot[i][r] = 0.f;
            }
#pragma unroll
        for (int j = 0; j < 8; j++) {
            const int col = cg * 128 + j * 16 + l15;
            const float wgv = aux[col];
#pragma unroll
            for (int i = 0; i < 4; i++)
#pragma unroll
                for (int r = 0; r < 4; r++) {
                    const float qn = acc[i][j][r] * sc[i][r];
                    outp[ro[i][r] + col] = (half_t)qn;
                    dot[i][r] += qn * wgv;
                }
        }
#pragma unroll
        for (int i = 0; i < 4; i++)
#pragma unroll
            for (int r = 0; r < 4; r++)
#pragma unroll
                for (int m = 1; m < 16; m <<= 1)
                    dot[i][r] += __shfl_xor(dot[i][r], m, 64);
        if (l15 == 0) {
#pragma unroll
            for (int i = 0; i < 4; i++)
#pragma unroll
                for (int r = 0; r < 4; r++)
                    red[cg * 128 + rg * 64 + i * 16 + quad * 4 + r] = dot[i][r];
        }
        __syncthreads();
        if (tid < 128) {
            const int gr = bm * 128 + tid;
            const int b = gr / TA, t = gr - b * TA;
            fout[b * NT + COFF + t] = SCALE_ *
                (red[tid] + red[128 + tid] + red[256 + tid] + red[384 + tid]);
        }
    } else {
        // MODE 2: kg = l2norm(k) * g[b,col]
#pragma unroll
        for (int j = 0; j < 8; j++) {
            const int col = cg * 128 + j * 16 + l15;
#pragma unroll
            for (int i = 0; i < 4; i++)
#pragma unroll
                for (int r = 0; r < 4; r++) {
                    const int gr = bm * 128 + rg * 64 + i * 16 + quad * 4 + r;
                    const float gv = aux[rowb[i][r] * 512 + col];
                    outp[(size_t)gr * 512 + col] =
                        (half_t)(acc[i][j][r] * sc[i][r] * gv);
                }
        }
    }
}

// ---------------------------------------------------------------- softmax (per batch) + zero g
__global__ __launch_bounds__(256) void softmax_w(
    float* __restrict__ araw, float* __restrict__ g)
{
    const int b = blockIdx.x;
    float* a = araw + (size_t)b * NT;
    g[b * D_ + threadIdx.x] = 0.f;
    g[b * D_ + 256 + threadIdx.x] = 0.f;
    __shared__ float red[8];
    const int lane = threadIdx.x & 63, wave = threadIdx.x >> 6;
    float m = -1e30f;
    for (int i = threadIdx.x; i < NT; i += 256) m = fmaxf(m, a[i]);
#pragma unroll
    for (int off = 32; off > 0; off >>= 1) m = fmaxf(m, __shfl_xor(m, off, 64));
    if (lane == 0) red[wave] = m;
    __syncthreads();
    m = fmaxf(fmaxf(red[0], red[1]), fmaxf(red[2], red[3]));
    float s = 0.f;
    for (int i = threadIdx.x; i < NT; i += 256) s += expf(a[i] - m);
#pragma unroll
    for (int off = 32; off > 0; off >>= 1) s += __shfl_xor(s, off, 64);
    if (lane == 0) red[4 + wave] = s;
    __syncthreads();
    s = red[4] + red[5] + red[6] + red[7];
    const float inv = 1.0f / s;
    for (int i = threadIdx.x; i < NT; i += 256) a[i] = expf(a[i] - m) * inv;
}

// ---------------------------------------------------------------- g = sum_n a_n * q_n
__global__ __launch_bounds__(256) void accum_g(
    const float* __restrict__ w, const half_t* __restrict__ qb, float* __restrict__ g)
{
    __shared__ float red[4][512];
    const int b = blockIdx.y, tid = threadIdx.x, lane = tid & 63, wave = tid >> 6;
    const int t0 = blockIdx.x * 227;
    const int t1 = (t0 + 227 < NT) ? t0 + 227 : NT;
    float a[8];
#pragma unroll
    for (int r = 0; r < 8; r++) a[r] = 0.f;
    for (int n = t0 + wave; n < t1; n += 4) {
        const float wn = w[(size_t)b * NT + n];
        half8 v = *(const half8*)&qb[((size_t)b * NT + n) * 512 + lane * 8];
#pragma unroll
        for (int r = 0; r < 8; r++) a[r] += wn * (float)v[r];
    }
#pragma unroll
    for (int r = 0; r < 8; r++) red[wave][lane * 8 + r] = a[r];
    __syncthreads();
    for (int d = tid; d < 512; d += 256)
        atomicAdd(&g[b * 512 + d], red[0][d] + red[1][d] + red[2][d] + red[3][d]);
}

// ---------------------------------------------------------------- launch
extern "C" void kernel_launch(void* const* d_in, const int* in_sizes, int n_in,
                              void* d_out, int out_size, void* d_ws, size_t ws_size,
                              hipStream_t stream)
{
    const float* verts  = (const float*)d_in[0];
    const float* imgf   = (const float*)d_in[1];
    const float* fc_w   = (const float*)d_in[2];
    const float* fc_b   = (const float*)d_in[3];
    const float* q_w    = (const float*)d_in[4];
    const float* q_b    = (const float*)d_in[5];
    const float* k_w    = (const float*)d_in[6];
    const float* k_b    = (const float*)d_in[7];
    const float* w_g    = (const float*)d_in[8];
    const float* proj_w = (const float*)d_in[9];
    const float* proj_b = (const float*)d_in[10];
    const float* fin_w  = (const float*)d_in[11];
    const float* fin_b  = (const float*)d_in[12];

    char* ws = (char*)d_ws;
    size_t off = 0;
    auto alloc = [&](size_t bytes) -> void* {
        void* p = ws + off;
        off += (bytes + 255) & ~(size_t)255;
        return p;
    };
    half_t* vb    = (half_t*)alloc((size_t)MV * D_ * 2);
    half_t* ib    = (half_t*)alloc((size_t)MI * IMGD * 2);
    half_t* fcwb  = (half_t*)alloc((size_t)D_ * IMGD * 2);
    half_t* qwb   = (half_t*)alloc((size_t)D_ * D_ * 2);
    half_t* kwb   = (half_t*)alloc((size_t)D_ * D_ * 2);
    half_t* fwb   = (half_t*)alloc((size_t)D_ * D_ * 2);
    half_t* pwtb  = (half_t*)alloc((size_t)D_ * D_ * 2);
    half_t* w2    = (half_t*)alloc((size_t)D_ * D_ * 2);
    half_t* imgp  = (half_t*)alloc((size_t)MI * D_ * 2);
    half_t* qb    = (half_t*)alloc((size_t)MQ * D_ * 2);
    half_t* kg    = (half_t*)alloc((size_t)MV * D_ * 2);
    float*  araw  = (float*)alloc((size_t)MQ * 4);
    float*  g     = (float*)alloc((size_t)B_ * D_ * 4);
    float*  bias2 = (float*)alloc((size_t)D_ * 4);

    convert_all<<<4096, 256, 0, stream>>>(verts, imgf, fc_w, q_w, k_w, fin_w,
                                          vb, ib, fcwb, qwb, kwb, fwb);
    transpose_pw<<<512, 256, 0, stream>>>(proj_w, pwtb);
    make_bias2<<<2, 256, 0, stream>>>(proj_b, fin_w, fin_b, bias2);
    // W2 = F @ P
    gemm_bt<4><<<dim3(4, 4), 256, 0, stream>>>(fwb, pwtb, nullptr, D_, w2);
    // imgp = img_f @ fc_w^T + fc_b
    gemm_bt<0><<<dim3(MI / 128, 4), 256, 0, stream>>>(ib, fcwb, fc_b, IMGD, imgp);
    // q-hat over vert rows and img rows (full-N, l2norm + logits fused)
    gemm_fn<1, NV, 0><<<MV / 128, 512, 0, stream>>>(
        vb, nullptr, qwb, nullptr, q_b, w_g, nullptr, qb, araw);
    gemm_fn<1, NI, NV><<<MI / 128, 512, 0, stream>>>(
        imgp, nullptr, qwb, nullptr, q_b, w_g, nullptr, qb, araw);
    softmax_w<<<B_, 256, 0, stream>>>(araw, g);
    accum_g<<<dim3(8, B_), 256, 0, stream>>>(araw, qb, g);
    // kg = l2norm(verts @ k_w^T + k_b) * g
    gemm_fn<2, NV, 0><<<MV / 128, 512, 0, stream>>>(
        vb, nullptr, kwb, nullptr, k_b, g, nullptr, kg, nullptr);
    // out = vb + bias2 + kg @ W2^T + q-hat @ F^T
    gemm_fn<3, NV, 0><<<MV / 128, 512, 0, stream>>>(
        kg, qb, w2, fwb, bias2, nullptr, vb, nullptr, (float*)d_out);
}

// Round 4
// 600.684 us; speedup vs baseline: 1.1026x; 1.1026x over previous
//
#include <hip/hip_runtime.h>

#define B_    32
#define NV    1556
#define NI    256
#define NT    1812          // NV + NI
#define D_    512
#define IMGD  2048
#define MV    (B_*NV)       // 49792 = 389*128
#define MI    (B_*NI)       // 8192  = 64*128
#define MQ    (B_*NT)       // 57984
#define SCALE_ 0.08838834764831845f   // (512/4)^-0.5

typedef _Float16 half_t;
typedef __attribute__((ext_vector_type(4))) _Float16 half4;
typedef __attribute__((ext_vector_type(8))) _Float16 half8;
typedef __attribute__((ext_vector_type(4))) float floatx4;

__device__ __forceinline__ void gload16(const void* g, void* l) {
    __builtin_amdgcn_global_load_lds(
        (const __attribute__((address_space(1))) void*)g,
        (__attribute__((address_space(3))) void*)l, 16, 0, 0);
}

// Swizzle: LDS rows are 64B (4x 16B slots); slot s of row r holds global
// k-chunk s ^ ((r>>1)&3). Staging source permutes chunks within the row
// (coalescing preserved); fragment read applies the same involution ->
// 2-way bank aliasing only (free).

// ---------------------------------------------------------------- convert
__global__ __launch_bounds__(256) void convert_all(
    const float* __restrict__ verts, const float* __restrict__ img,
    const float* __restrict__ w2, const float* __restrict__ w3,
    const float* __restrict__ w4, const float* __restrict__ w5,
    half_t* __restrict__ o0, half_t* __restrict__ o1, half_t* __restrict__ o2,
    half_t* __restrict__ o3, half_t* __restrict__ o4, half_t* __restrict__ o5)
{
    const long E0 = (long)MV * D_;
    const long E1 = (long)MI * IMGD;
    const long E2 = (long)D_ * IMGD;
    const long E3 = (long)D_ * D_;
    const long total4 = (E0 + E1 + E2 + 3 * E3) / 4;
    for (long i = blockIdx.x * (long)blockDim.x + threadIdx.x; i < total4;
         i += (long)gridDim.x * blockDim.x) {
        long e = i * 4;
        const float* s; half_t* d;
        if (e < E0)              { s = verts; d = o0; }
        else if ((e -= E0) < E1) { s = img;   d = o1; }
        else if ((e -= E1) < E2) { s = w2;    d = o2; }
        else if ((e -= E2) < E3) { s = w3;    d = o3; }
        else if ((e -= E3) < E3) { s = w4;    d = o4; }
        else                     { e -= E3; s = w5; d = o5; }
        float4 x = *(const float4*)(s + e);
        half4 h = { (half_t)x.x, (half_t)x.y, (half_t)x.z, (half_t)x.w };
        *(half4*)(d + e) = h;
    }
}

// pwt[d,e] = proj_w[e,d]  (f16)
__global__ __launch_bounds__(256) void transpose_pw(
    const float* __restrict__ P, half_t* __restrict__ pwt)
{
    const int n = blockIdx.x;
    for (int d = threadIdx.x; d < 512; d += 256)
        pwt[(size_t)n * 512 + d] = (half_t)P[(size_t)d * 512 + n];
}

// bias2[f] = sum_d pb[d]*F[f,d] + fb[f]
__global__ __launch_bounds__(256) void make_bias2(
    const float* __restrict__ pb, const float* __restrict__ F,
    const float* __restrict__ fb, float* __restrict__ bias2)
{
    const int n = blockIdx.x * 256 + threadIdx.x;
    float s = fb[n];
    for (int d = 0; d < 512; d++) s += pb[d] * F[(size_t)n * 512 + d];
    bias2[n] = s;
}

// ---------------------------------------------------------------- basic 128x128 GEMM
// 3 buffers, prefetch depth 2, counted vmcnt (LDS only 24KB -> many blocks/CU).
template<int MODE>
__global__ __launch_bounds__(256) void gemm_bt(
    const half_t* __restrict__ A, const half_t* __restrict__ Bw,
    const float* __restrict__ bias, int K, half_t* __restrict__ Ch)
{
    __shared__ __align__(16) half_t As[3][128 * 32];
    __shared__ __align__(16) half_t Bs[3][128 * 32];
    const int tid  = threadIdx.x;
    const int lane = tid & 63;
    const int wave = tid >> 6;
    const int quad = lane >> 4, l15 = lane & 15;
    const int wr = (wave >> 1) * 64;
    const int wc = (wave & 1) * 64;
    const int bm = blockIdx.x, bn = blockIdx.y;

    floatx4 acc[4][4];
#pragma unroll
    for (int i = 0; i < 4; i++)
#pragma unroll
        for (int j = 0; j < 4; j++) acc[i][j] = (floatx4){0.f, 0.f, 0.f, 0.f};

    const int r0  = tid >> 2;
    const int akp = ((tid & 3) ^ ((tid >> 3) & 3)) * 8;   // swizzled k-chunk
    const half_t* ag0 = A  + (size_t)(bm * 128 + r0) * K + akp;
    const half_t* ag1 = A  + (size_t)(bm * 128 + 64 + r0) * K + akp;
    const half_t* bg0 = Bw + (size_t)(bn * 128 + r0) * K + akp;
    const half_t* bg1 = Bw + (size_t)(bn * 128 + 64 + r0) * K + akp;

    auto stage = [&](int t, int buf) {
        const int k0 = t * 32;
        gload16(ag0 + k0, &As[buf][tid * 8]);
        gload16(ag1 + k0, &As[buf][(tid + 256) * 8]);
        gload16(bg0 + k0, &Bs[buf][tid * 8]);
        gload16(bg1 + k0, &Bs[buf][(tid + 256) * 8]);
    };
    const int frr = l15 * 32 + ((quad ^ ((l15 >> 1) & 3)) << 3);
    auto do_tile = [&](int buf) {
        half8 a[4], b[4];
#pragma unroll
        for (int i = 0; i < 4; i++)
            a[i] = *(const half8*)&As[buf][(wr + i * 16) * 32 + frr];
#pragma unroll
        for (int j = 0; j < 4; j++)
            b[j] = *(const half8*)&Bs[buf][(wc + j * 16) * 32 + frr];
#pragma unroll
        for (int i = 0; i < 4; i++)
#pragma unroll
            for (int j = 0; j < 4; j++)
                acc[i][j] = __builtin_amdgcn_mfma_f32_16x16x32_f16(
                    a[i], b[j], acc[i][j], 0, 0, 0);
    };

    const int NIT = K >> 5;
    stage(0, 0);
    stage(1, 1);
    int cur = 0;
    for (int t = 0; t < NIT - 1; ++t) {
        asm volatile("s_waitcnt vmcnt(4) lgkmcnt(0)" ::: "memory");
        __builtin_amdgcn_s_barrier();
        asm volatile("" ::: "memory");
        int nb = cur + 2; if (nb >= 3) nb -= 3;
        if (t + 2 < NIT) stage(t + 2, nb);
        do_tile(cur);
        cur++; if (cur == 3) cur = 0;
    }
    asm volatile("s_waitcnt vmcnt(0) lgkmcnt(0)" ::: "memory");
    __builtin_amdgcn_s_barrier();
    asm volatile("" ::: "memory");
    do_tile(cur);

    const int colbase = bn * 128 + wc + l15;
    const int rowbase = bm * 128 + wr + (quad << 2);
#pragma unroll
    for (int i = 0; i < 4; i++)
#pragma unroll
        for (int j = 0; j < 4; j++) {
            const int col = colbase + j * 16;
            const float bv = (MODE == 0) ? bias[col] : 0.f;
#pragma unroll
            for (int r = 0; r < 4; r++) {
                const int grow = rowbase + i * 16 + r;
                Ch[(size_t)grow * D_ + col] = (half_t)(acc[i][j][r] + bv);
            }
        }
}

// ---------------------------------------------------------------- full-N GEMM (128 rows x 512 cols)
// r2-proven structure: 2 buffers, stage(t+1) before compute(t), __syncthreads.
// MODES 1/2 only (need full-row reductions).
template<int MODE, int TA, int COFF>
__global__ __launch_bounds__(512, 2) void gemm_fn(
    const half_t* __restrict__ A, const half_t* __restrict__ Bw,
    const float* __restrict__ bias, const float* __restrict__ aux,
    half_t* __restrict__ outp, float* __restrict__ fout)
{
    __shared__ __align__(16) half_t As[2][128 * 32];   // 16 KB
    __shared__ __align__(16) half_t Bs[2][512 * 32];   // 64 KB
    // red[512] + scale_l[128] aliased onto As (dead after K-loop) -> 80KB total
    float* red     = (float*)&As[0][0];
    float* scale_l = red + 512;

    const int tid = threadIdx.x, lane = tid & 63, wave = tid >> 6;
    const int rg = wave >> 2, cg = wave & 3;
    const int quad = lane >> 4, l15 = lane & 15;
    const int bm = blockIdx.x;

    const int arow = tid >> 2;
    const int akp  = ((tid & 3) ^ ((tid >> 3) & 3)) * 8;   // swizzled k-chunk
    const int gr_a = bm * 128 + arow;
    const half_t* ag0 = A + (size_t)gr_a * 512 + akp;
    size_t boff[4];
#pragma unroll
    for (int s = 0; s < 4; s++)
        boff[s] = (size_t)(arow + 128 * s) * 512 + akp;

    floatx4 acc[4][8];
#pragma unroll
    for (int i = 0; i < 4; i++)
#pragma unroll
        for (int j = 0; j < 8; j++) acc[i][j] = (floatx4){0.f, 0.f, 0.f, 0.f};

    auto stage = [&](int t, int buf) {
        const int k0 = t * 32;
        gload16(ag0 + k0, &As[buf][tid * 8]);
#pragma unroll
        for (int s = 0; s < 4; s++)
            gload16(Bw + boff[s] + k0, &Bs[buf][(tid + 512 * s) * 8]);
    };

    stage(0, 0);
    __syncthreads();
    const int frr = l15 * 32 + ((quad ^ ((l15 >> 1) & 3)) << 3);
    int cur = 0;
    for (int t = 0; t < 16; ++t) {
        if (t + 1 < 16) stage(t + 1, cur ^ 1);
        half8 a[4], b[8];
#pragma unroll
        for (int i = 0; i < 4; i++)
            a[i] = *(const half8*)&As[cur][(rg * 64 + i * 16) * 32 + frr];
#pragma unroll
        for (int j = 0; j < 8; j++)
            b[j] = *(const half8*)&Bs[cur][(cg * 128 + j * 16) * 32 + frr];
#pragma unroll
        for (int i = 0; i < 4; i++)
#pragma unroll
            for (int j = 0; j < 8; j++)
                acc[i][j] = __builtin_amdgcn_mfma_f32_16x16x32_f16(
                    a[i], b[j], acc[i][j], 0, 0, 0);
        __syncthreads();
        cur ^= 1;
    }

    // ---- bias + row sum-of-squares
    float ssq[4][4];
#pragma unroll
    for (int i = 0; i < 4; i++)
#pragma unroll
        for (int r = 0; r < 4; r++) ssq[i][r] = 0.f;
#pragma unroll
    for (int j = 0; j < 8; j++) {
        const float bv = bias[cg * 128 + j * 16 + l15];
#pragma unroll
        for (int i = 0; i < 4; i++)
#pragma unroll
            for (int r = 0; r < 4; r++) {
                float v = acc[i][j][r] + bv;
                acc[i][j][r] = v;
                ssq[i][r] += v * v;
            }
    }
#pragma unroll
    for (int i = 0; i < 4; i++)
#pragma unroll
        for (int r = 0; r < 4; r++)
#pragma unroll
            for (int m = 1; m < 16; m <<= 1)
                ssq[i][r] += __shfl_xor(ssq[i][r], m, 64);
    if (l15 == 0) {
#pragma unroll
        for (int i = 0; i < 4; i++)
#pragma unroll
            for (int r = 0; r < 4; r++)
                red[cg * 128 + rg * 64 + i * 16 + quad * 4 + r] = ssq[i][r];
    }
    __syncthreads();
    if (tid < 128)
        scale_l[tid] = 1.f / fmaxf(
            sqrtf(red[tid] + red[128 + tid] + red[256 + tid] + red[384 + tid]),
            1e-12f);
    __syncthreads();

    float sc[4][4];
    int rowb[4][4], rowt[4][4];
#pragma unroll
    for (int i = 0; i < 4; i++)
#pragma unroll
        for (int r = 0; r < 4; r++) {
            const int li = rg * 64 + i * 16 + quad * 4 + r;
            sc[i][r] = scale_l[li];
            const int gr = bm * 128 + li;
            const int b = gr / TA;
            rowb[i][r] = b;
            rowt[i][r] = gr - b * TA;
        }
    __syncthreads();   // scale_l/red fully read before any LDS reuse

    if (MODE == 1) {
        size_t ro[4][4];
        float dot[4][4];
#pragma unroll
        for (int i = 0; i < 4; i++)
#pragma unroll
            for (int r = 0; r < 4; r++) {
                ro[i][r] = ((size_t)rowb[i][r] * NT + COFF + rowt[i][r]) * 512;
                dot[i][r] = 0.f;
            }
#pragma unroll
        for (int j = 0; j < 8; j++) {
            const int col = cg * 128 + j * 16 + l15;
            const float wgv = aux[col];
#pragma unroll
            for (int i = 0; i < 4; i++)
#pragma unroll
                for (int r = 0; r < 4; r++) {
                    const float qn = acc[i][j][r] * sc[i][r];
                    outp[ro[i][r] + col] = (half_t)qn;
                    dot[i][r] += qn * wgv;
                }
        }
#pragma unroll
        for (int i = 0; i < 4; i++)
#pragma unroll
            for (int r = 0; r < 4; r++)
#pragma unroll
                for (int m = 1; m < 16; m <<= 1)
                    dot[i][r] += __shfl_xor(dot[i][r], m, 64);
        if (l15 == 0) {
#pragma unroll
            for (int i = 0; i < 4; i++)
#pragma unroll
                for (int r = 0; r < 4; r++)
                    red[cg * 128 + rg * 64 + i * 16 + quad * 4 + r] = dot[i][r];
        }
        __syncthreads();
        if (tid < 128) {
            const int gr = bm * 128 + tid;
            const int b = gr / TA, t = gr - b * TA;
            fout[b * NT + COFF + t] = SCALE_ *
                (red[tid] + red[128 + tid] + red[256 + tid] + red[384 + tid]);
        }
    } else {
        // MODE 2: kg = l2norm(k) * g[b,col]
#pragma unroll
        for (int j = 0; j < 8; j++) {
            const int col = cg * 128 + j * 16 + l15;
#pragma unroll
            for (int i = 0; i < 4; i++)
#pragma unroll
                for (int r = 0; r < 4; r++) {
                    const int gr = bm * 128 + rg * 64 + i * 16 + quad * 4 + r;
                    const float gv = aux[rowb[i][r] * 512 + col];
                    outp[(size_t)gr * 512 + col] =
                        (half_t)(acc[i][j][r] * sc[i][r] * gv);
                }
        }
    }
}

// ---------------------------------------------------------------- final GEMM
// out = kg @ W2^T + qb @ F^T + bias2 + vres.  Tile 128x256, grid (MV/128, 2),
// 3 LDS buffers (72KB -> 2 blocks/CU), prefetch depth 2, counted vmcnt.
__global__ __launch_bounds__(512, 4) void gemm_f3(
    const half_t* __restrict__ A, const half_t* __restrict__ A2,
    const half_t* __restrict__ Bw, const half_t* __restrict__ Bw2,
    const float* __restrict__ bias, const half_t* __restrict__ vres,
    float* __restrict__ fout)
{
    __shared__ __align__(16) half_t As[3][128 * 32];   // 24 KB
    __shared__ __align__(16) half_t Bs[3][256 * 32];   // 48 KB

    const int tid = threadIdx.x, lane = tid & 63, wave = tid >> 6;
    const int rg = wave >> 2, cg = wave & 3;
    const int quad = lane >> 4, l15 = lane & 15;
    const int bm = blockIdx.x, bn = blockIdx.y;

    const int arow = tid >> 2;
    const int akp  = ((tid & 3) ^ ((tid >> 3) & 3)) * 8;   // swizzled k-chunk
    const int gr_a = bm * 128 + arow;
    const half_t* ag0 = A + (size_t)gr_a * 512 + akp;
    const int bb_ = gr_a / NV, tt_ = gr_a - bb_ * NV;
    const half_t* ag1 = A2 + ((size_t)bb_ * NT + tt_) * 512 + akp;
    size_t boff[2];
#pragma unroll
    for (int s = 0; s < 2; s++)
        boff[s] = (size_t)(bn * 256 + arow + 128 * s) * 512 + akp;

    floatx4 acc[4][4];
#pragma unroll
    for (int i = 0; i < 4; i++)
#pragma unroll
        for (int j = 0; j < 4; j++) acc[i][j] = (floatx4){0.f, 0.f, 0.f, 0.f};

    auto stage = [&](int t, int buf) {
        const half_t* ag = (t < 16) ? ag0 : ag1;
        const half_t* bw = (t < 16) ? Bw : Bw2;
        const int k0 = (t & 15) * 32;
        gload16(ag + k0, &As[buf][tid * 8]);
#pragma unroll
        for (int s = 0; s < 2; s++)
            gload16(bw + boff[s] + k0, &Bs[buf][(tid + 512 * s) * 8]);
    };
    const int frr = l15 * 32 + ((quad ^ ((l15 >> 1) & 3)) << 3);
    auto do_tile = [&](int buf) {
        half8 a[4], b[4];
#pragma unroll
        for (int i = 0; i < 4; i++)
            a[i] = *(const half8*)&As[buf][(rg * 64 + i * 16) * 32 + frr];
#pragma unroll
        for (int j = 0; j < 4; j++)
            b[j] = *(const half8*)&Bs[buf][(cg * 64 + j * 16) * 32 + frr];
#pragma unroll
        for (int i = 0; i < 4; i++)
#pragma unroll
            for (int j = 0; j < 4; j++)
                acc[i][j] = __builtin_amdgcn_mfma_f32_16x16x32_f16(
                    a[i], b[j], acc[i][j], 0, 0, 0);
    };

    const int NIT = 32;
    stage(0, 0);
    stage(1, 1);
    int cur = 0;
    for (int t = 0; t < NIT - 1; ++t) {
        asm volatile("s_waitcnt vmcnt(3) lgkmcnt(0)" ::: "memory");
        __builtin_amdgcn_s_barrier();
        asm volatile("" ::: "memory");
        int nb = cur + 2; if (nb >= 3) nb -= 3;
        if (t + 2 < NIT) stage(t + 2, nb);
        do_tile(cur);
        cur++; if (cur == 3) cur = 0;
    }
    asm volatile("s_waitcnt vmcnt(0) lgkmcnt(0)" ::: "memory");
    __builtin_amdgcn_s_barrier();
    asm volatile("" ::: "memory");
    do_tile(cur);

#pragma unroll
    for (int j = 0; j < 4; j++) {
        const int col = bn * 256 + cg * 64 + j * 16 + l15;
        const float bv = bias[col];
#pragma unroll
        for (int i = 0; i < 4; i++)
#pragma unroll
            for (int r = 0; r < 4; r++) {
                const int gr = bm * 128 + rg * 64 + i * 16 + quad * 4 + r;
                const size_t idx = (size_t)gr * 512 + col;
                fout[idx] = acc[i][j][r] + bv + (float)vres[idx];
            }
    }
}

// ---------------------------------------------------------------- softmax (per batch) + zero g
__global__ __launch_bounds__(256) void softmax_w(
    float* __restrict__ araw, float* __restrict__ g)
{
    const int b = blockIdx.x;
    float* a = araw + (size_t)b * NT;
    g[b * D_ + threadIdx.x] = 0.f;
    g[b * D_ + 256 + threadIdx.x] = 0.f;
    __shared__ float red[8];
    const int lane = threadIdx.x & 63, wave = threadIdx.x >> 6;
    float m = -1e30f;
    for (int i = threadIdx.x; i < NT; i += 256) m = fmaxf(m, a[i]);
#pragma unroll
    for (int off = 32; off > 0; off >>= 1) m = fmaxf(m, __shfl_xor(m, off, 64));
    if (lane == 0) red[wave] = m;
    __syncthreads();
    m = fmaxf(fmaxf(red[0], red[1]), fmaxf(red[2], red[3]));
    float s = 0.f;
    for (int i = threadIdx.x; i < NT; i += 256) s += expf(a[i] - m);
#pragma unroll
    for (int off = 32; off > 0; off >>= 1) s += __shfl_xor(s, off, 64);
    if (lane == 0) red[4 + wave] = s;
    __syncthreads();
    s = red[4] + red[5] + red[6] + red[7];
    const float inv = 1.0f / s;
    for (int i = threadIdx.x; i < NT; i += 256) a[i] = expf(a[i] - m) * inv;
}

// ---------------------------------------------------------------- g = sum_n a_n * q_n
__global__ __launch_bounds__(256) void accum_g(
    const float* __restrict__ w, const half_t* __restrict__ qb, float* __restrict__ g)
{
    __shared__ float red[4][512];
    const int b = blockIdx.y, tid = threadIdx.x, lane = tid & 63, wave = tid >> 6;
    const int t0 = blockIdx.x * 227;
    const int t1 = (t0 + 227 < NT) ? t0 + 227 : NT;
    float a[8];
#pragma unroll
    for (int r = 0; r < 8; r++) a[r] = 0.f;
    for (int n = t0 + wave; n < t1; n += 4) {
        const float wn = w[(size_t)b * NT + n];
        half8 v = *(const half8*)&qb[((size_t)b * NT + n) * 512 + lane * 8];
#pragma unroll
        for (int r = 0; r < 8; r++) a[r] += wn * (float)v[r];
    }
#pragma unroll
    for (int r = 0; r < 8; r++) red[wave][lane * 8 + r] = a[r];
    __syncthreads();
    for (int d = tid; d < 512; d += 256)
        atomicAdd(&g[b * 512 + d], red[0][d] + red[1][d] + red[2][d] + red[3][d]);
}

// ---------------------------------------------------------------- launch
extern "C" void kernel_launch(void* const* d_in, const int* in_sizes, int n_in,
                              void* d_out, int out_size, void* d_ws, size_t ws_size,
                              hipStream_t stream)
{
    const float* verts  = (const float*)d_in[0];
    const float* imgf   = (const float*)d_in[1];
    const float* fc_w   = (const float*)d_in[2];
    const float* fc_b   = (const float*)d_in[3];
    const float* q_w    = (const float*)d_in[4];
    const float* q_b    = (const float*)d_in[5];
    const float* k_w    = (const float*)d_in[6];
    const float* k_b    = (const float*)d_in[7];
    const float* w_g    = (const float*)d_in[8];
    const float* proj_w = (const float*)d_in[9];
    const float* proj_b = (const float*)d_in[10];
    const float* fin_w  = (const float*)d_in[11];
    const float* fin_b  = (const float*)d_in[12];

    char* ws = (char*)d_ws;
    size_t off = 0;
    auto alloc = [&](size_t bytes) -> void* {
        void* p = ws + off;
        off += (bytes + 255) & ~(size_t)255;
        return p;
    };
    half_t* vb    = (half_t*)alloc((size_t)MV * D_ * 2);
    half_t* ib    = (half_t*)alloc((size_t)MI * IMGD * 2);
    half_t* fcwb  = (half_t*)alloc((size_t)D_ * IMGD * 2);
    half_t* qwb   = (half_t*)alloc((size_t)D_ * D_ * 2);
    half_t* kwb   = (half_t*)alloc((size_t)D_ * D_ * 2);
    half_t* fwb   = (half_t*)alloc((size_t)D_ * D_ * 2);
    half_t* pwtb  = (half_t*)alloc((size_t)D_ * D_ * 2);
    half_t* w2    = (half_t*)alloc((size_t)D_ * D_ * 2);
    half_t* imgp  = (half_t*)alloc((size_t)MI * D_ * 2);
    half_t* qb    = (half_t*)alloc((size_t)MQ * D_ * 2);
    half_t* kg    = (half_t*)alloc((size_t)MV * D_ * 2);
    float*  araw  = (float*)alloc((size_t)MQ * 4);
    float*  g     = (float*)alloc((size_t)B_ * D_ * 4);
    float*  bias2 = (float*)alloc((size_t)D_ * 4);

    convert_all<<<4096, 256, 0, stream>>>(verts, imgf, fc_w, q_w, k_w, fin_w,
                                          vb, ib, fcwb, qwb, kwb, fwb);
    transpose_pw<<<512, 256, 0, stream>>>(proj_w, pwtb);
    make_bias2<<<2, 256, 0, stream>>>(proj_b, fin_w, fin_b, bias2);
    // W2 = F @ P
    gemm_bt<4><<<dim3(4, 4), 256, 0, stream>>>(fwb, pwtb, nullptr, D_, w2);
    // imgp = img_f @ fc_w^T + fc_b
    gemm_bt<0><<<dim3(MI / 128, 4), 256, 0, stream>>>(ib, fcwb, fc_b, IMGD, imgp);
    // q-hat over vert rows and img rows (full-N, l2norm + logits fused)
    gemm_fn<1, NV, 0><<<MV / 128, 512, 0, stream>>>(
        vb, qwb, q_b, w_g, qb, araw);
    gemm_fn<1, NI, NV><<<MI / 128, 512, 0, stream>>>(
        imgp, qwb, q_b, w_g, qb, araw);
    softmax_w<<<B_, 256, 0, stream>>>(araw, g);
    accum_g<<<dim3(8, B_), 256, 0, stream>>>(araw, qb, g);
    // kg = l2norm(verts @ k_w^T + k_b) * g
    gemm_fn<2, NV, 0><<<MV / 128, 512, 0, stream>>>(
        vb, kwb, k_b, g, kg, nullptr);
    // out = vb + bias2 + kg @ W2^T + q-hat @ F^T
    gemm_f3<<<dim3(MV / 128, 2), 512, 0, stream>>>(
        kg, qb, w2, fwb, bias2, vb, (float*)d_out);
}

// Round 5
// 548.833 us; speedup vs baseline: 1.2067x; 1.0945x over previous
//
#include <hip/hip_runtime.h>

#define B_    32
#define NV    1556
#define NI    256
#define NT    1812          // NV + NI
#define D_    512
#define IMGD  2048
#define MV    (B_*NV)       // 49792 = 389*128
#define MI    (B_*NI)       // 8192  = 64*128
#define MQ    (B_*NT)       // 57984
#define SCALE_ 0.08838834764831845f   // (512/4)^-0.5

typedef _Float16 half_t;
typedef __attribute__((ext_vector_type(4))) _Float16 half4;
typedef __attribute__((ext_vector_type(8))) _Float16 half8;
typedef __attribute__((ext_vector_type(4))) float floatx4;

__device__ __forceinline__ void gload16(const void* g, void* l) {
    __builtin_amdgcn_global_load_lds(
        (const __attribute__((address_space(1))) void*)g,
        (__attribute__((address_space(3))) void*)l, 16, 0, 0);
}

// Swizzle: LDS rows are 64B (4x 16B slots); slot s of row r holds global
// k-chunk s ^ ((r>>1)&3). Staging source permutes chunks within the row
// (coalescing preserved); fragment read applies the same involution ->
// 2-way bank aliasing only (free).

// row -> (batch, token) mapping for the virtual concat [vert rows | img rows]
__device__ __forceinline__ void maprow(int gr, int& b, int& tok) {
    if (gr < MV) { b = gr / NV; tok = gr - b * NV; }
    else { int gi = gr - MV; b = gi / NI; tok = gi - b * NI + NV; }
}

// ---------------------------------------------------------------- convert
__global__ __launch_bounds__(256) void convert_all(
    const float* __restrict__ verts, const float* __restrict__ img,
    const float* __restrict__ w2, const float* __restrict__ w3,
    const float* __restrict__ w4, const float* __restrict__ w5,
    half_t* __restrict__ o0, half_t* __restrict__ o1, half_t* __restrict__ o2,
    half_t* __restrict__ o3, half_t* __restrict__ o4, half_t* __restrict__ o5)
{
    const long E0 = (long)MV * D_;
    const long E1 = (long)MI * IMGD;
    const long E2 = (long)D_ * IMGD;
    const long E3 = (long)D_ * D_;
    const long total4 = (E0 + E1 + E2 + 3 * E3) / 4;
    for (long i = blockIdx.x * (long)blockDim.x + threadIdx.x; i < total4;
         i += (long)gridDim.x * blockDim.x) {
        long e = i * 4;
        const float* s; half_t* d;
        if (e < E0)              { s = verts; d = o0; }
        else if ((e -= E0) < E1) { s = img;   d = o1; }
        else if ((e -= E1) < E2) { s = w2;    d = o2; }
        else if ((e -= E2) < E3) { s = w3;    d = o3; }
        else if ((e -= E3) < E3) { s = w4;    d = o4; }
        else                     { e -= E3; s = w5; d = o5; }
        float4 x = *(const float4*)(s + e);
        half4 h = { (half_t)x.x, (half_t)x.y, (half_t)x.z, (half_t)x.w };
        *(half4*)(d + e) = h;
    }
}

// pwt[d,e] = proj_w[e,d]  (f16)
__global__ __launch_bounds__(256) void transpose_pw(
    const float* __restrict__ P, half_t* __restrict__ pwt)
{
    const int n = blockIdx.x;
    for (int d = threadIdx.x; d < 512; d += 256)
        pwt[(size_t)n * 512 + d] = (half_t)P[(size_t)d * 512 + n];
}

// bias2[f] = sum_d pb[d]*F[f,d] + fb[f]
__global__ __launch_bounds__(256) void make_bias2(
    const float* __restrict__ pb, const float* __restrict__ F,
    const float* __restrict__ fb, float* __restrict__ bias2)
{
    const int n = blockIdx.x * 256 + threadIdx.x;
    float s = fb[n];
    for (int d = 0; d < 512; d++) s += pb[d] * F[(size_t)n * 512 + d];
    bias2[n] = s;
}

// ---------------------------------------------------------------- basic 128x128 GEMM
// 3 buffers, prefetch depth 2, counted vmcnt (LDS only 24KB -> many blocks/CU).
template<int MODE>
__global__ __launch_bounds__(256) void gemm_bt(
    const half_t* __restrict__ A, const half_t* __restrict__ Bw,
    const float* __restrict__ bias, int K, half_t* __restrict__ Ch)
{
    __shared__ __align__(16) half_t As[3][128 * 32];
    __shared__ __align__(16) half_t Bs[3][128 * 32];
    const int tid  = threadIdx.x;
    const int lane = tid & 63;
    const int wave = tid >> 6;
    const int quad = lane >> 4, l15 = lane & 15;
    const int wr = (wave >> 1) * 64;
    const int wc = (wave & 1) * 64;
    const int bm = blockIdx.x, bn = blockIdx.y;

    floatx4 acc[4][4];
#pragma unroll
    for (int i = 0; i < 4; i++)
#pragma unroll
        for (int j = 0; j < 4; j++) acc[i][j] = (floatx4){0.f, 0.f, 0.f, 0.f};

    const int r0  = tid >> 2;
    const int akp = ((tid & 3) ^ ((tid >> 3) & 3)) * 8;   // swizzled k-chunk
    const half_t* ag0 = A  + (size_t)(bm * 128 + r0) * K + akp;
    const half_t* ag1 = A  + (size_t)(bm * 128 + 64 + r0) * K + akp;
    const half_t* bg0 = Bw + (size_t)(bn * 128 + r0) * K + akp;
    const half_t* bg1 = Bw + (size_t)(bn * 128 + 64 + r0) * K + akp;

    auto stage = [&](int t, int buf) {
        const int k0 = t * 32;
        gload16(ag0 + k0, &As[buf][tid * 8]);
        gload16(ag1 + k0, &As[buf][(tid + 256) * 8]);
        gload16(bg0 + k0, &Bs[buf][tid * 8]);
        gload16(bg1 + k0, &Bs[buf][(tid + 256) * 8]);
    };
    const int frr = l15 * 32 + ((quad ^ ((l15 >> 1) & 3)) << 3);
    auto do_tile = [&](int buf) {
        half8 a[4], b[4];
#pragma unroll
        for (int i = 0; i < 4; i++)
            a[i] = *(const half8*)&As[buf][(wr + i * 16) * 32 + frr];
#pragma unroll
        for (int j = 0; j < 4; j++)
            b[j] = *(const half8*)&Bs[buf][(wc + j * 16) * 32 + frr];
#pragma unroll
        for (int i = 0; i < 4; i++)
#pragma unroll
            for (int j = 0; j < 4; j++)
                acc[i][j] = __builtin_amdgcn_mfma_f32_16x16x32_f16(
                    a[i], b[j], acc[i][j], 0, 0, 0);
    };

    const int NIT = K >> 5;
    stage(0, 0);
    stage(1, 1);
    int cur = 0;
    for (int t = 0; t < NIT - 1; ++t) {
        asm volatile("s_waitcnt vmcnt(4) lgkmcnt(0)" ::: "memory");
        __builtin_amdgcn_s_barrier();
        asm volatile("" ::: "memory");
        int nb = cur + 2; if (nb >= 3) nb -= 3;
        if (t + 2 < NIT) stage(t + 2, nb);
        do_tile(cur);
        cur++; if (cur == 3) cur = 0;
    }
    asm volatile("s_waitcnt vmcnt(0) lgkmcnt(0)" ::: "memory");
    __builtin_amdgcn_s_barrier();
    asm volatile("" ::: "memory");
    do_tile(cur);

    const int colbase = bn * 128 + wc + l15;
    const int rowbase = bm * 128 + wr + (quad << 2);
#pragma unroll
    for (int i = 0; i < 4; i++)
#pragma unroll
        for (int j = 0; j < 4; j++) {
            const int col = colbase + j * 16;
            const float bv = (MODE == 0) ? bias[col] : 0.f;
#pragma unroll
            for (int r = 0; r < 4; r++) {
                const int grow = rowbase + i * 16 + r;
                Ch[(size_t)grow * D_ + col] = (half_t)(acc[i][j][r] + bv);
            }
        }
}

// ---------------------------------------------------------------- full-N GEMM (128 rows x 512 cols)
// Pipeline: Bs double-buffered via global_load_lds with COUNTED vmcnt(1)
// (B is L2-resident, 1-phase flight is enough); A reg-staged (T14):
// global->reg issued 2 iters ahead, ds_write post-MFMA (compiler inserts the
// per-reg counted wait), consumed next iter. LDS exactly 80KB -> 2 blocks/CU.
// MODE 1: q-hat + logits (merged vert+img rows).  MODE 2: kg.
template<int MODE>
__global__ __launch_bounds__(512, 2) void gemm_fn(
    const half_t* __restrict__ Av, const half_t* __restrict__ Ai,
    const half_t* __restrict__ Bw,
    const float* __restrict__ bias, const float* __restrict__ aux,
    half_t* __restrict__ outp, float* __restrict__ fout)
{
    __shared__ __align__(16) half_t As[2][128 * 32];   // 16 KB
    __shared__ __align__(16) half_t Bs[2][512 * 32];   // 64 KB
    float* red     = (float*)&As[0][0];
    float* scale_l = red + 512;

    const int tid = threadIdx.x, lane = tid & 63, wave = tid >> 6;
    const int rg = wave >> 2, cg = wave & 3;
    const int quad = lane >> 4, l15 = lane & 15;
    const int bm = blockIdx.x;

    const int arow = tid >> 2;
    const int akp  = ((tid & 3) ^ ((tid >> 3) & 3)) * 8;   // swizzled k-chunk
    const int gr_a = bm * 128 + arow;
    const half_t* agp = (gr_a < MV)
        ? Av + (size_t)gr_a * 512 + akp
        : Ai + (size_t)(gr_a - MV) * 512 + akp;
    size_t boff[4];
#pragma unroll
    for (int s = 0; s < 4; s++)
        boff[s] = (size_t)(arow + 128 * s) * 512 + akp;

    floatx4 acc[4][8];
#pragma unroll
    for (int i = 0; i < 4; i++)
#pragma unroll
        for (int j = 0; j < 8; j++) acc[i][j] = (floatx4){0.f, 0.f, 0.f, 0.f};

    auto stageB = [&](int t, int buf) {
        const int k0 = t * 32;
#pragma unroll
        for (int s = 0; s < 4; s++)
            gload16(Bw + boff[s] + k0, &Bs[buf][(tid + 512 * s) * 8]);
    };
    const int frr = l15 * 32 + ((quad ^ ((l15 >> 1) & 3)) << 3);
    auto do_tile = [&](int buf) {
        half8 a[4], b[8];
#pragma unroll
        for (int i = 0; i < 4; i++)
            a[i] = *(const half8*)&As[buf][(rg * 64 + i * 16) * 32 + frr];
#pragma unroll
        for (int j = 0; j < 8; j++)
            b[j] = *(const half8*)&Bs[buf][(cg * 128 + j * 16) * 32 + frr];
#pragma unroll
        for (int i = 0; i < 4; i++)
#pragma unroll
            for (int j = 0; j < 8; j++)
                acc[i][j] = __builtin_amdgcn_mfma_f32_16x16x32_f16(
                    a[i], b[j], acc[i][j], 0, 0, 0);
    };

    // prologue: A(0) direct to LDS, B(0) to LDS, A(1) to reg
    gload16(agp, &As[0][tid * 8]);            // 1 vm (oldest)
    stageB(0, 0);                             // 4 vm
    half8 arA = *(const half8*)(agp + 32);    // A(1) -> reg, 1 vm
    half8 arB;

#pragma unroll
    for (int t = 0; t < 16; t += 2) {
        // ---------------- even iter t: bufs 0, aIn=arA(A(t+1)), aOut=arB
        asm volatile("s_waitcnt vmcnt(1) lgkmcnt(0)" ::: "memory");
        __builtin_amdgcn_s_barrier();
        asm volatile("" ::: "memory");
        stageB(t + 1, 1);                               // 4 vm
        if (t + 2 < 16) arB = *(const half8*)(agp + (t + 2) * 32);  // 1 vm
        do_tile(0);
        __builtin_amdgcn_sched_barrier(0);
        *(half8*)&As[1][tid * 8] = arA;                 // A(t+1) for iter t+1
        // ---------------- odd iter t+1: bufs 1, aIn=arB(A(t+2)), aOut=arA
        if (t + 1 == 15) asm volatile("s_waitcnt vmcnt(0) lgkmcnt(0)" ::: "memory");
        else             asm volatile("s_waitcnt vmcnt(1) lgkmcnt(0)" ::: "memory");
        __builtin_amdgcn_s_barrier();
        asm volatile("" ::: "memory");
        if (t + 2 < 16) stageB(t + 2, 0);               // 4 vm
        if (t + 3 < 16) arA = *(const half8*)(agp + (t + 3) * 32);  // 1 vm
        do_tile(1);
        if (t + 2 < 16) {
            __builtin_amdgcn_sched_barrier(0);
            *(half8*)&As[0][tid * 8] = arB;             // A(t+2) for iter t+2
        }
    }

    __syncthreads();   // all waves past final ds_reads before red-alias writes

    // ---- bias + row sum-of-squares
    float ssq[4][4];
#pragma unroll
    for (int i = 0; i < 4; i++)
#pragma unroll
        for (int r = 0; r < 4; r++) ssq[i][r] = 0.f;
#pragma unroll
    for (int j = 0; j < 8; j++) {
        const float bv = bias[cg * 128 + j * 16 + l15];
#pragma unroll
        for (int i = 0; i < 4; i++)
#pragma unroll
            for (int r = 0; r < 4; r++) {
                float v = acc[i][j][r] + bv;
                acc[i][j][r] = v;
                ssq[i][r] += v * v;
            }
    }
#pragma unroll
    for (int i = 0; i < 4; i++)
#pragma unroll
        for (int r = 0; r < 4; r++)
#pragma unroll
            for (int m = 1; m < 16; m <<= 1)
                ssq[i][r] += __shfl_xor(ssq[i][r], m, 64);
    if (l15 == 0) {
#pragma unroll
        for (int i = 0; i < 4; i++)
#pragma unroll
            for (int r = 0; r < 4; r++)
                red[cg * 128 + rg * 64 + i * 16 + quad * 4 + r] = ssq[i][r];
    }
    __syncthreads();
    if (tid < 128)
        scale_l[tid] = 1.f / fmaxf(
            sqrtf(red[tid] + red[128 + tid] + red[256 + tid] + red[384 + tid]),
            1e-12f);
    __syncthreads();

    float sc[4][4];
    int rowb[4][4], rowt[4][4];
#pragma unroll
    for (int i = 0; i < 4; i++)
#pragma unroll
        for (int r = 0; r < 4; r++) {
            const int li = rg * 64 + i * 16 + quad * 4 + r;
            sc[i][r] = scale_l[li];
            maprow(bm * 128 + li, rowb[i][r], rowt[i][r]);
        }
    __syncthreads();   // scale_l/red fully read before any LDS reuse

    if (MODE == 1) {
        size_t ro[4][4];
        float dot[4][4];
#pragma unroll
        for (int i = 0; i < 4; i++)
#pragma unroll
            for (int r = 0; r < 4; r++) {
                ro[i][r] = ((size_t)rowb[i][r] * NT + rowt[i][r]) * 512;
                dot[i][r] = 0.f;
            }
#pragma unroll
        for (int j = 0; j < 8; j++) {
            const int col = cg * 128 + j * 16 + l15;
            const float wgv = aux[col];
#pragma unroll
            for (int i = 0; i < 4; i++)
#pragma unroll
                for (int r = 0; r < 4; r++) {
                    const float qn = acc[i][j][r] * sc[i][r];
                    outp[ro[i][r] + col] = (half_t)qn;
                    dot[i][r] += qn * wgv;
                }
        }
#pragma unroll
        for (int i = 0; i < 4; i++)
#pragma unroll
            for (int r = 0; r < 4; r++)
#pragma unroll
                for (int m = 1; m < 16; m <<= 1)
                    dot[i][r] += __shfl_xor(dot[i][r], m, 64);
        if (l15 == 0) {
#pragma unroll
            for (int i = 0; i < 4; i++)
#pragma unroll
                for (int r = 0; r < 4; r++)
                    red[cg * 128 + rg * 64 + i * 16 + quad * 4 + r] = dot[i][r];
        }
        __syncthreads();
        if (tid < 128) {
            int b, tok;
            maprow(bm * 128 + tid, b, tok);
            fout[b * NT + tok] = SCALE_ *
                (red[tid] + red[128 + tid] + red[256 + tid] + red[384 + tid]);
        }
    } else {
        // MODE 2: kg = l2norm(k) * g[b,col]
#pragma unroll
        for (int j = 0; j < 8; j++) {
            const int col = cg * 128 + j * 16 + l15;
#pragma unroll
            for (int i = 0; i < 4; i++)
#pragma unroll
                for (int r = 0; r < 4; r++) {
                    const int gr = bm * 128 + rg * 64 + i * 16 + quad * 4 + r;
                    const float gv = aux[rowb[i][r] * 512 + col];
                    outp[(size_t)gr * 512 + col] =
                        (half_t)(acc[i][j][r] * sc[i][r] * gv);
                }
        }
    }
}

// ---------------------------------------------------------------- final GEMM
// out = kg @ W2^T + qb @ F^T + bias2 + vres.  Tile 128x256, 778 blocks
// (pair-adjacent ids), bijective chunked XCD swizzle so (bm,0)/(bm,1) share
// an XCD L2 (A rows deduped). 3 LDS buffers (72KB -> 2 blocks/CU), depth-2
// counted vmcnt.
__global__ __launch_bounds__(512, 4) void gemm_f3(
    const half_t* __restrict__ A, const half_t* __restrict__ A2,
    const half_t* __restrict__ Bw, const half_t* __restrict__ Bw2,
    const float* __restrict__ bias, const half_t* __restrict__ vres,
    float* __restrict__ fout)
{
    __shared__ __align__(16) half_t As[3][128 * 32];   // 24 KB
    __shared__ __align__(16) half_t Bs[3][256 * 32];   // 48 KB

    const int tid = threadIdx.x, lane = tid & 63, wave = tid >> 6;
    const int rg = wave >> 2, cg = wave & 3;
    const int quad = lane >> 4, l15 = lane & 15;

    // bijective chunked XCD swizzle (nwg=778, q=97, r=2)
    const int id = blockIdx.x;
    const int xcd = id & 7, off = id >> 3;
    const int wg = (xcd < 2 ? xcd * 98 : 2 * 98 + (xcd - 2) * 97) + off;
    const int bm = wg >> 1, bn = wg & 1;

    const int arow = tid >> 2;
    const int akp  = ((tid & 3) ^ ((tid >> 3) & 3)) * 8;   // swizzled k-chunk
    const int gr_a = bm * 128 + arow;
    const half_t* ag0 = A + (size_t)gr_a * 512 + akp;
    const int bb_ = gr_a / NV, tt_ = gr_a - bb_ * NV;
    const half_t* ag1 = A2 + ((size_t)bb_ * NT + tt_) * 512 + akp;
    size_t boff[2];
#pragma unroll
    for (int s = 0; s < 2; s++)
        boff[s] = (size_t)(bn * 256 + arow + 128 * s) * 512 + akp;

    floatx4 acc[4][4];
#pragma unroll
    for (int i = 0; i < 4; i++)
#pragma unroll
        for (int j = 0; j < 4; j++) acc[i][j] = (floatx4){0.f, 0.f, 0.f, 0.f};

    auto stage = [&](int t, int buf) {
        const half_t* ag = (t < 16) ? ag0 : ag1;
        const half_t* bw = (t < 16) ? Bw : Bw2;
        const int k0 = (t & 15) * 32;
        gload16(ag + k0, &As[buf][tid * 8]);
#pragma unroll
        for (int s = 0; s < 2; s++)
            gload16(bw + boff[s] + k0, &Bs[buf][(tid + 512 * s) * 8]);
    };
    const int frr = l15 * 32 + ((quad ^ ((l15 >> 1) & 3)) << 3);
    auto do_tile = [&](int buf) {
        half8 a[4], b[4];
#pragma unroll
        for (int i = 0; i < 4; i++)
            a[i] = *(const half8*)&As[buf][(rg * 64 + i * 16) * 32 + frr];
#pragma unroll
        for (int j = 0; j < 4; j++)
            b[j] = *(const half8*)&Bs[buf][(cg * 64 + j * 16) * 32 + frr];
#pragma unroll
        for (int i = 0; i < 4; i++)
#pragma unroll
            for (int j = 0; j < 4; j++)
                acc[i][j] = __builtin_amdgcn_mfma_f32_16x16x32_f16(
                    a[i], b[j], acc[i][j], 0, 0, 0);
    };

    const int NIT = 32;
    stage(0, 0);
    stage(1, 1);
    int cur = 0;
    for (int t = 0; t < NIT - 1; ++t) {
        asm volatile("s_waitcnt vmcnt(3) lgkmcnt(0)" ::: "memory");
        __builtin_amdgcn_s_barrier();
        asm volatile("" ::: "memory");
        int nb = cur + 2; if (nb >= 3) nb -= 3;
        if (t + 2 < NIT) stage(t + 2, nb);
        do_tile(cur);
        cur++; if (cur == 3) cur = 0;
    }
    asm volatile("s_waitcnt vmcnt(0) lgkmcnt(0)" ::: "memory");
    __builtin_amdgcn_s_barrier();
    asm volatile("" ::: "memory");
    do_tile(cur);

#pragma unroll
    for (int j = 0; j < 4; j++) {
        const int col = bn * 256 + cg * 64 + j * 16 + l15;
        const float bv = bias[col];
#pragma unroll
        for (int i = 0; i < 4; i++)
#pragma unroll
            for (int r = 0; r < 4; r++) {
                const int gr = bm * 128 + rg * 64 + i * 16 + quad * 4 + r;
                const size_t idx = (size_t)gr * 512 + col;
                fout[idx] = acc[i][j][r] + bv + (float)vres[idx];
            }
    }
}

// ---------------------------------------------------------------- softmax (per batch) + zero g
__global__ __launch_bounds__(256) void softmax_w(
    float* __restrict__ araw, float* __restrict__ g)
{
    const int b = blockIdx.x;
    float* a = araw + (size_t)b * NT;
    g[b * D_ + threadIdx.x] = 0.f;
    g[b * D_ + 256 + threadIdx.x] = 0.f;
    __shared__ float red[8];
    const int lane = threadIdx.x & 63, wave = threadIdx.x >> 6;
    float m = -1e30f;
    for (int i = threadIdx.x; i < NT; i += 256) m = fmaxf(m, a[i]);
#pragma unroll
    for (int off = 32; off > 0; off >>= 1) m = fmaxf(m, __shfl_xor(m, off, 64));
    if (lane == 0) red[wave] = m;
    __syncthreads();
    m = fmaxf(fmaxf(red[0], red[1]), fmaxf(red[2], red[3]));
    float s = 0.f;
    for (int i = threadIdx.x; i < NT; i += 256) s += expf(a[i] - m);
#pragma unroll
    for (int off = 32; off > 0; off >>= 1) s += __shfl_xor(s, off, 64);
    if (lane == 0) red[4 + wave] = s;
    __syncthreads();
    s = red[4] + red[5] + red[6] + red[7];
    const float inv = 1.0f / s;
    for (int i = threadIdx.x; i < NT; i += 256) a[i] = expf(a[i] - m) * inv;
}

// ---------------------------------------------------------------- g = sum_n a_n * q_n
__global__ __launch_bounds__(256) void accum_g(
    const float* __restrict__ w, const half_t* __restrict__ qb, float* __restrict__ g)
{
    __shared__ float red[4][512];
    const int b = blockIdx.y, tid = threadIdx.x, lane = tid & 63, wave = tid >> 6;
    const int t0 = blockIdx.x * 227;
    const int t1 = (t0 + 227 < NT) ? t0 + 227 : NT;
    float a[8];
#pragma unroll
    for (int r = 0; r < 8; r++) a[r] = 0.f;
    for (int n = t0 + wave; n < t1; n += 4) {
        const float wn = w[(size_t)b * NT + n];
        half8 v = *(const half8*)&qb[((size_t)b * NT + n) * 512 + lane * 8];
#pragma unroll
        for (int r = 0; r < 8; r++) a[r] += wn * (float)v[r];
    }
#pragma unroll
    for (int r = 0; r < 8; r++) red[wave][lane * 8 + r] = a[r];
    __syncthreads();
    for (int d = tid; d < 512; d += 256)
        atomicAdd(&g[b * 512 + d], red[0][d] + red[1][d] + red[2][d] + red[3][d]);
}

// ---------------------------------------------------------------- launch
extern "C" void kernel_launch(void* const* d_in, const int* in_sizes, int n_in,
                              void* d_out, int out_size, void* d_ws, size_t ws_size,
                              hipStream_t stream)
{
    const float* verts  = (const float*)d_in[0];
    const float* imgf   = (const float*)d_in[1];
    const float* fc_w   = (const float*)d_in[2];
    const float* fc_b   = (const float*)d_in[3];
    const float* q_w    = (const float*)d_in[4];
    const float* q_b    = (const float*)d_in[5];
    const float* k_w    = (const float*)d_in[6];
    const float* k_b    = (const float*)d_in[7];
    const float* w_g    = (const float*)d_in[8];
    const float* proj_w = (const float*)d_in[9];
    const float* proj_b = (const float*)d_in[10];
    const float* fin_w  = (const float*)d_in[11];
    const float* fin_b  = (const float*)d_in[12];

    char* ws = (char*)d_ws;
    size_t off = 0;
    auto alloc = [&](size_t bytes) -> void* {
        void* p = ws + off;
        off += (bytes + 255) & ~(size_t)255;
        return p;
    };
    half_t* vb    = (half_t*)alloc((size_t)MV * D_ * 2);
    half_t* ib    = (half_t*)alloc((size_t)MI * IMGD * 2);
    half_t* fcwb  = (half_t*)alloc((size_t)D_ * IMGD * 2);
    half_t* qwb   = (half_t*)alloc((size_t)D_ * D_ * 2);
    half_t* kwb   = (half_t*)alloc((size_t)D_ * D_ * 2);
    half_t* fwb   = (half_t*)alloc((size_t)D_ * D_ * 2);
    half_t* pwtb  = (half_t*)alloc((size_t)D_ * D_ * 2);
    half_t* w2    = (half_t*)alloc((size_t)D_ * D_ * 2);
    half_t* imgp  = (half_t*)alloc((size_t)MI * D_ * 2);
    half_t* qb    = (half_t*)alloc((size_t)MQ * D_ * 2);
    half_t* kg    = (half_t*)alloc((size_t)MV * D_ * 2);
    float*  araw  = (float*)alloc((size_t)MQ * 4);
    float*  g     = (float*)alloc((size_t)B_ * D_ * 4);
    float*  bias2 = (float*)alloc((size_t)D_ * 4);

    convert_all<<<4096, 256, 0, stream>>>(verts, imgf, fc_w, q_w, k_w, fin_w,
                                          vb, ib, fcwb, qwb, kwb, fwb);
    transpose_pw<<<512, 256, 0, stream>>>(proj_w, pwtb);
    make_bias2<<<2, 256, 0, stream>>>(proj_b, fin_w, fin_b, bias2);
    // W2 = F @ P
    gemm_bt<4><<<dim3(4, 4), 256, 0, stream>>>(fwb, pwtb, nullptr, D_, w2);
    // imgp = img_f @ fc_w^T + fc_b
    gemm_bt<0><<<dim3(MI / 128, 4), 256, 0, stream>>>(ib, fcwb, fc_b, IMGD, imgp);
    // q-hat over ALL rows (vert + img merged), l2norm + logits fused
    gemm_fn<1><<<(MV + MI) / 128, 512, 0, stream>>>(
        vb, imgp, qwb, q_b, w_g, qb, araw);
    softmax_w<<<B_, 256, 0, stream>>>(araw, g);
    accum_g<<<dim3(8, B_), 256, 0, stream>>>(araw, qb, g);
    // kg = l2norm(verts @ k_w^T + k_b) * g
    gemm_fn<2><<<MV / 128, 512, 0, stream>>>(
        vb, nullptr, kwb, k_b, g, kg, nullptr);
    // out = vb + bias2 + kg @ W2^T + q-hat @ F^T
    gemm_f3<<<778, 512, 0, stream>>>(
        kg, qb, w2, fwb, bias2, vb, (float*)d_out);
}